// Round 7
// baseline (347.027 us; speedup 1.0000x reference)
//
#include <hip/hip_runtime.h>
#include <hip/hip_bf16.h>
#include <math.h>

typedef __bf16 bf16_t;
typedef __bf16 bf16x8 __attribute__((ext_vector_type(8)));
typedef float f32x4 __attribute__((ext_vector_type(4)));

constexpr int Bc = 2, Tc = 2048, Cdim = 2048, Hc = 16, KVc = 4, HDc = 128;
constexpr int Mc = Bc * Tc;      // 4096
constexpr int Nqkv = 3072;       // fused projection width: 2048 Q + 512 K + 512 V

typedef const __attribute__((address_space(1))) void* as1_cptr;
typedef __attribute__((address_space(3))) void* as3_ptr;

__device__ __forceinline__ void gload_lds16(const bf16_t* g, bf16_t* l) {
  __builtin_amdgcn_global_load_lds((as1_cptr)(const void*)g, (as3_ptr)(void*)l, 16, 0, 0);
}

// ---------------- elementwise f32 -> bf16 (x) ----------------
__global__ void k_cvt_bf16(const float* __restrict__ in, bf16_t* __restrict__ out) {
  int i = (blockIdx.x * 256 + threadIdx.x) * 8;
  float4 a = *(const float4*)(in + i);
  float4 b = *(const float4*)(in + i + 4);
  bf16x8 v;
  v[0] = (bf16_t)a.x; v[1] = (bf16_t)a.y; v[2] = (bf16_t)a.z; v[3] = (bf16_t)a.w;
  v[4] = (bf16_t)b.x; v[5] = (bf16_t)b.y; v[6] = (bf16_t)b.z; v[7] = (bf16_t)b.w;
  *(bf16x8*)(out + i) = v;
}

// ------- fused QKV weight transpose: {Wq,Wk,Wv}[K,N] -> Wqkvt[3072][2048] ----
__global__ void k_wqkv_trans(const float* __restrict__ Wq, const float* __restrict__ Wk,
                             const float* __restrict__ Wv, bf16_t* __restrict__ Wt) {
  __shared__ alignas(16) bf16_t tile[64][72];
  const int k0 = blockIdx.x * 64, n0 = blockIdx.y * 64;  // n0 in fused 0..3071
  const float* src; int srcN, ncol0;
  if (n0 < 2048)      { src = Wq; srcN = 2048; ncol0 = n0; }
  else if (n0 < 2560) { src = Wk; srcN = 512;  ncol0 = n0 - 2048; }
  else                { src = Wv; srcN = 512;  ncol0 = n0 - 2560; }
  const int t = threadIdx.x;
#pragma unroll
  for (int i = 0; i < 4; ++i) {
    int idx = t + i * 256;
    int r = idx >> 4;
    int c4 = (idx & 15) * 4;
    float4 v = *(const float4*)(src + (size_t)(k0 + r) * srcN + ncol0 + c4);
    tile[r][c4 + 0] = (bf16_t)v.x; tile[r][c4 + 1] = (bf16_t)v.y;
    tile[r][c4 + 2] = (bf16_t)v.z; tile[r][c4 + 3] = (bf16_t)v.w;
  }
  __syncthreads();
#pragma unroll
  for (int i = 0; i < 4; ++i) {
    int idx = t + i * 256;
    int n = idx >> 4;
    int kc = (idx & 15) * 4;
    alignas(8) bf16_t o[4];
#pragma unroll
    for (int j = 0; j < 4; ++j) o[j] = tile[kc + j][n];
    *(uint2*)(Wt + (size_t)(n0 + n) * Cdim + k0 + kc) = *(uint2*)o;
  }
}

// ---------------- W [K,N] f32 -> Wt [N,K] bf16 (for Wo) -------
__global__ void k_w_trans(const float* __restrict__ W, bf16_t* __restrict__ Wt,
                          int K, int N) {
  __shared__ alignas(16) bf16_t tile[64][72];
  const int k0 = blockIdx.x * 64, n0 = blockIdx.y * 64;
  const int t = threadIdx.x;
#pragma unroll
  for (int i = 0; i < 4; ++i) {
    int idx = t + i * 256;
    int r = idx >> 4;
    int c4 = (idx & 15) * 4;
    float4 v = *(const float4*)(W + (size_t)(k0 + r) * N + n0 + c4);
    tile[r][c4 + 0] = (bf16_t)v.x; tile[r][c4 + 1] = (bf16_t)v.y;
    tile[r][c4 + 2] = (bf16_t)v.z; tile[r][c4 + 3] = (bf16_t)v.w;
  }
  __syncthreads();
#pragma unroll
  for (int i = 0; i < 4; ++i) {
    int idx = t + i * 256;
    int n = idx >> 4;
    int kc = (idx & 15) * 4;
    alignas(8) bf16_t o[4];
#pragma unroll
    for (int j = 0; j < 4; ++j) o[j] = tile[kc + j][n];
    *(uint2*)(Wt + (size_t)(n0 + n) * K + k0 + kc) = *(uint2*)o;
  }
}

// ---------------- GEMM: C[M,N] = A[M,K] * Bt[N,K]^T ----------
// (256,3): VGPR cap ~170 -> 3 blocks/CU (m97's regime). Needs ~135, no spill.
template <typename OutT>
__global__ __launch_bounds__(256, 3) void k_gemm_bt(
    const bf16_t* __restrict__ A, const bf16_t* __restrict__ Bt,
    OutT* __restrict__ Cout, int M, int N, int K) {
  __shared__ alignas(16) bf16_t Ash[128 * 64];
  __shared__ alignas(16) bf16_t Bsh[128 * 64];
  const int tid = threadIdx.x;
  const int wave = tid >> 6, lane = tid & 63;
  const int col = lane & 15, quad = lane >> 4;
  const int m0 = blockIdx.y * 128, n0 = blockIdx.x * 128;
  const int wr = wave >> 1, wc = wave & 1;

  f32x4 acc[4][4];
#pragma unroll
  for (int i = 0; i < 4; ++i)
#pragma unroll
    for (int j = 0; j < 4; ++j) acc[i][j] = f32x4{0.f, 0.f, 0.f, 0.f};

  const int lrow = lane >> 3;
  const int lkc8 = (lane & 7) ^ lrow;

  for (int k0 = 0; k0 < K; k0 += 64) {
    __syncthreads();
#pragma unroll
    for (int i = 0; i < 4; ++i) {
      const int rb = wave * 32 + i * 8;
      gload_lds16(A + (size_t)(m0 + rb + lrow) * K + k0 + lkc8 * 8, Ash + rb * 64);
      gload_lds16(Bt + (size_t)(n0 + rb + lrow) * K + k0 + lkc8 * 8, Bsh + rb * 64);
    }
    __syncthreads();
#pragma unroll
    for (int kc = 0; kc < 2; ++kc) {
      bf16x8 af[4], bfr[4];
#pragma unroll
      for (int mt = 0; mt < 4; ++mt) {
        const int m = wr * 64 + mt * 16 + col;
        const int slot = (kc * 4 + quad) ^ (m & 7);
        af[mt] = *(const bf16x8*)(Ash + m * 64 + slot * 8);
      }
#pragma unroll
      for (int nt = 0; nt < 4; ++nt) {
        const int n = wc * 64 + nt * 16 + col;
        const int slot = (kc * 4 + quad) ^ (n & 7);
        bfr[nt] = *(const bf16x8*)(Bsh + n * 64 + slot * 8);
      }
#pragma unroll
      for (int mt = 0; mt < 4; ++mt)
#pragma unroll
        for (int nt = 0; nt < 4; ++nt)
          acc[mt][nt] = __builtin_amdgcn_mfma_f32_16x16x32_bf16(
              af[mt], bfr[nt], acc[mt][nt], 0, 0, 0);
    }
  }
#pragma unroll
  for (int mt = 0; mt < 4; ++mt)
#pragma unroll
    for (int i = 0; i < 4; ++i) {
      const int row = m0 + wr * 64 + mt * 16 + quad * 4 + i;
#pragma unroll
      for (int nt = 0; nt < 4; ++nt)
        Cout[(size_t)row * N + n0 + wc * 64 + nt * 16 + col] = (OutT)acc[mt][nt][i];
    }
}

// ---------------- fused RoPE (Q and K) + head-major repack ----
__global__ void k_rope2(const bf16_t* __restrict__ in, const float* __restrict__ cs,
                        const float* __restrict__ sn, bf16_t* __restrict__ outQ,
                        bf16_t* __restrict__ outK) {
  const int idx = blockIdx.x * 256 + threadIdx.x;
  const int d = idx & 63;
  const int hh = (idx >> 6) % 20;
  const int bt = idx / (64 * 20);
  const int t = bt & (Tc - 1);
  const int b = bt >> 11;
  const bool isQ = hh < 16;
  const int h = isQ ? hh : hh - 16;
  const int colb = isQ ? h * HDc : 2048 + h * HDc;
  const size_t bi = (size_t)(b * Tc + t) * Nqkv + colb;
  const float x0 = (float)in[bi + d];
  const float x1 = (float)in[bi + d + 64];
  const float c0 = cs[t * HDc + d], c1 = cs[t * HDc + d + 64];
  const float s0 = sn[t * HDc + d], s1 = sn[t * HDc + d + 64];
  bf16_t* op = isQ ? outQ + ((size_t)(b * Hc + h) * Tc + t) * HDc
                   : outK + ((size_t)(b * KVc + h) * Tc + t) * HDc;
  op[d]      = (bf16_t)(x0 * c0 - x1 * s0);
  op[d + 64] = (bf16_t)(x1 * c1 + x0 * s1);
}

// ---------------- V repack: fused rows -> [B,KV,HD,T] --------
__global__ void k_vtrans(const bf16_t* __restrict__ v, bf16_t* __restrict__ vt,
                         int in_stride, int col_off) {
  __shared__ alignas(16) bf16_t tile[64][136];
  const int t0 = blockIdx.x * 64;
  const int kv = blockIdx.y, b = blockIdx.z;
  const int tid = threadIdx.x;
#pragma unroll
  for (int i = 0; i < 4; ++i) {
    int idx = tid + i * 256;
    int r = idx >> 4;
    int ch = idx & 15;
    const bf16_t* gp = v + (size_t)(b * Tc + t0 + r) * in_stride + col_off + kv * HDc + ch * 8;
    *(uint4*)&tile[r][ch * 8] = *(const uint4*)gp;
  }
  __syncthreads();
#pragma unroll
  for (int i = 0; i < 4; ++i) {
    int idx = tid + i * 256;
    int d = idx >> 3;
    int tc = idx & 7;
    alignas(16) bf16_t o[8];
#pragma unroll
    for (int j = 0; j < 8; ++j) o[j] = tile[tc * 8 + j][d];
    bf16_t* gp = vt + ((size_t)(b * KVc + kv) * HDc + d) * Tc + t0 + tc * 8;
    *(uint4*)gp = *(uint4*)o;
  }
}

// ---------------- Flash attention v7: 512-thread blocks ------
// 8 waves share one K/V tile; q-tile = 128 rows (two 64-row wave groups,
// per-group diagonal). LDS = 2x16K(K)+2x16K(V)+16K(P) = 80 KB -> 2 blocks/CU
// = 16 waves/CU = 4 waves/SIMD (double v6). Per-wave fragment code identical
// to v6 (no-max exp2 softmax, dbuf + s_barrier + vmcnt(4)).
// Balance: qt = b ? 15-x : x -> co-resident blocks on a CU pair to 36 iters.
__global__ __launch_bounds__(512, 2) void k_attn(
    const bf16_t* __restrict__ Qp, const bf16_t* __restrict__ Kp,
    const bf16_t* __restrict__ Vt, bf16_t* __restrict__ Oout) {
  constexpr float sc2 = 0.08838834764831845f * 1.4426950408889634f; // scale*log2(e)
  __shared__ alignas(16) bf16_t Ksh[2][64 * 128];   // 16 slots, swizzled ^(r&7)
  __shared__ alignas(16) bf16_t Vsh[2][128 * 64];   // 8 slots, swizzled ^(d&7)
  __shared__ alignas(16) bf16_t Psh[8][16 * 64];    // per-wave P 16x64, XOR-swizzled

  const int h = blockIdx.y, b = blockIdx.z;
  const int qt = b ? (15 - blockIdx.x) : blockIdx.x;
  const int kvh = h >> 2;  // REP = 4
  const int tid = threadIdx.x, wave = tid >> 6, lane = tid & 63;
  const int grp = wave >> 2, wsub = wave & 3;
  const int col = lane & 15, quad = lane >> 4;
  const int q0 = qt * 128 + grp * 64 + wsub * 16;

  const int dtile = 2 * qt + grp;   // this wave-group's diagonal kv-tile
  const int niter = 2 * qt + 2;

  const bf16_t* Kb = Kp + (size_t)(b * KVc + kvh) * Tc * HDc;
  const bf16_t* Vb = Vt + (size_t)(b * KVc + kvh) * HDc * Tc;
  const bf16_t* Qbh = Qp + (size_t)(b * Hc + h) * Tc * HDc;

  // staging: 8 waves cover K 64x128 (wave w: rows w*8..w*8+7, 2 instrs)
  // and V 128x64 (wave w: d w*16..w*16+15, 2 instrs)
  const int st_kr = lane >> 4, st_kc8 = lane & 15;
  const int st_vr = lane >> 3, st_vc8 = lane & 7;

  // Q fragments pre-scaled by scale*log2(e)
  bf16x8 qf[4];
  {
    const bf16_t* qbase = Qbh + (size_t)(q0 + col) * HDc;
#pragma unroll
    for (int kc = 0; kc < 4; ++kc) {
      bf16x8 raw = *(const bf16x8*)(qbase + kc * 32 + quad * 8);
#pragma unroll
      for (int e = 0; e < 8; ++e) qf[kc][e] = (bf16_t)((float)raw[e] * sc2);
    }
  }

  f32x4 o_acc[8];
#pragma unroll
  for (int nb = 0; nb < 8; ++nb) o_acc[nb] = f32x4{0.f, 0.f, 0.f, 0.f};
  float l_i[4] = {0.f, 0.f, 0.f, 0.f};

  // prologue: stage tile 0 into buffer 0 (4 loads/wave)
#pragma unroll
  for (int i = 0; i < 2; ++i) {
    const int rb = wave * 8 + i * 4;
    const int r = rb + st_kr;
    const int kc8 = st_kc8 ^ (r & 7);
    gload_lds16(Kb + (size_t)r * HDc + kc8 * 8, &Ksh[0][rb * 128]);
    const int db = wave * 16 + i * 8;
    const int d = db + st_vr;
    const int tc8 = st_vc8 ^ (d & 7);
    gload_lds16(Vb + (size_t)d * Tc + tc8 * 8, &Vsh[0][db * 64]);
  }

#pragma unroll 1
  for (int j = 0; j < niter; ++j) {
    const int cur = j & 1;
    // all waves done reading buffer cur^1
    asm volatile("s_barrier" ::: "memory");
    // prefetch next tile into cur^1 (clamped; keeps vmcnt uniform)
    {
      const int jn = (j + 1 < niter) ? (j + 1) : (niter - 1);
      const int kbn = jn * 64;
#pragma unroll
      for (int i = 0; i < 2; ++i) {
        const int rb = wave * 8 + i * 4;
        const int r = rb + st_kr;
        const int kc8 = st_kc8 ^ (r & 7);
        gload_lds16(Kb + (size_t)(kbn + r) * HDc + kc8 * 8, &Ksh[cur ^ 1][rb * 128]);
        const int db = wave * 16 + i * 8;
        const int d = db + st_vr;
        const int tc8 = st_vc8 ^ (d & 7);
        gload_lds16(Vb + (size_t)d * Tc + kbn + tc8 * 8, &Vsh[cur ^ 1][db * 64]);
      }
    }
    // wait for tile j (4 oldest); next tile's 4 stay in flight
    asm volatile("s_waitcnt vmcnt(4)" ::: "memory");
    asm volatile("s_barrier" ::: "memory");

    if (j <= dtile) {
      const bool diag = (j == dtile);
      const bf16_t* Kc = &Ksh[cur][0];
      const bf16_t* Vc = &Vsh[cur][0];

      // S = Q K^T : 16 q-rows x 64 kv
      f32x4 st[4];
#pragma unroll
      for (int tb = 0; tb < 4; ++tb) st[tb] = f32x4{0.f, 0.f, 0.f, 0.f};
#pragma unroll
      for (int kc = 0; kc < 4; ++kc)
#pragma unroll
        for (int tb = 0; tb < 4; ++tb) {
          const int r = tb * 16 + col;
          const int slot = (kc * 4 + quad) ^ (r & 7);
          bf16x8 kf = *(const bf16x8*)(Kc + r * 128 + slot * 8);
          st[tb] = __builtin_amdgcn_mfma_f32_16x16x32_bf16(qf[kc], kf, st[tb], 0, 0, 0);
        }

      // p = exp2(s); zero-mask on diagonal tile; plain l accumulation
      bf16_t* pw = &Psh[wave][0];
      const int rowthr = wsub * 16 + quad * 4;
#pragma unroll
      for (int i = 0; i < 4; ++i) {
        float e0 = exp2f(st[0][i]), e1 = exp2f(st[1][i]);
        float e2 = exp2f(st[2][i]), e3 = exp2f(st[3][i]);
        if (diag) {
          const int thr = rowthr + i;
          if (col      > thr) e0 = 0.f;
          if (16 + col > thr) e1 = 0.f;
          if (32 + col > thr) e2 = 0.f;
          if (48 + col > thr) e3 = 0.f;
        }
        l_i[i] += (e0 + e1) + (e2 + e3);
        const int r7 = (quad * 4 + i) & 7;
        const int rbase = (quad * 4 + i) * 64;
        const int c7 = col & 7, ch = col >> 3;
        pw[rbase + ((ch    ) ^ r7) * 8 + c7] = (bf16_t)e0;
        pw[rbase + ((ch + 2) ^ r7) * 8 + c7] = (bf16_t)e1;
        pw[rbase + ((ch + 4) ^ r7) * 8 + c7] = (bf16_t)e2;
        pw[rbase + ((ch + 6) ^ r7) * 8 + c7] = (bf16_t)e3;
      }
      asm volatile("s_waitcnt lgkmcnt(0)" ::: "memory");

      // O += P V
#pragma unroll
      for (int kc = 0; kc < 2; ++kc) {
        const int slot = ((kc * 4) + quad) ^ (col & 7);
        const bf16x8 pf = *(const bf16x8*)(pw + col * 64 + slot * 8);
#pragma unroll
        for (int nb = 0; nb < 8; ++nb) {
          const int d = nb * 16 + col;
          const int vslot = (kc * 4 + quad) ^ (d & 7);
          bf16x8 vf = *(const bf16x8*)(Vc + d * 64 + vslot * 8);
          o_acc[nb] = __builtin_amdgcn_mfma_f32_16x16x32_bf16(pf, vf, o_acc[nb], 0, 0, 0);
        }
      }
    }
  }
  // drain leftover prefetch before block teardown
  asm volatile("s_waitcnt vmcnt(0)" ::: "memory");

  // epilogue: one cross-lane l reduction, write O
#pragma unroll
  for (int i = 0; i < 4; ++i) {
    float rs = l_i[i];
    rs += __shfl_xor(rs, 1);
    rs += __shfl_xor(rs, 2);
    rs += __shfl_xor(rs, 4);
    rs += __shfl_xor(rs, 8);
    const float inv = 1.0f / rs;
    const int qrow = q0 + quad * 4 + i;
    bf16_t* op = Oout + ((size_t)(b * Tc) + qrow) * (Hc * HDc) + h * HDc;
#pragma unroll
    for (int nb = 0; nb < 8; ++nb) op[nb * 16 + col] = (bf16_t)(o_acc[nb][i] * inv);
  }
}

// ---------------- launch ----------------
extern "C" void kernel_launch(void* const* d_in, const int* in_sizes, int n_in,
                              void* d_out, int out_size, void* d_ws, size_t ws_size,
                              hipStream_t stream) {
  (void)in_sizes; (void)n_in; (void)out_size; (void)ws_size;
  const float* x    = (const float*)d_in[0];
  const float* cosT = (const float*)d_in[1];
  const float* sinT = (const float*)d_in[2];
  const float* Wq   = (const float*)d_in[3];
  const float* Wk   = (const float*)d_in[4];
  const float* Wv   = (const float*)d_in[5];
  const float* Wo   = (const float*)d_in[6];
  float* out = (float*)d_out;

  char* ws = (char*)d_ws;
  size_t off = 0;
  auto take = [&](size_t bytes) { char* p = ws + off; off += (bytes + 255) & ~(size_t)255; return p; };

  bf16_t* xb    = (bf16_t*)take((size_t)Mc * Cdim * 2);      // reused as Qp after proj
  bf16_t* Wqkvt = (bf16_t*)take((size_t)Nqkv * Cdim * 2);    // [3072][2048]
  bf16_t* Wot   = (bf16_t*)take((size_t)Cdim * (Hc * HDc) * 2);
  bf16_t* qkv   = (bf16_t*)take((size_t)Mc * Nqkv * 2);      // reused as attn out
  bf16_t* Kp    = (bf16_t*)take((size_t)Mc * (KVc * HDc) * 2);
  bf16_t* Vt    = (bf16_t*)take((size_t)Mc * (KVc * HDc) * 2);
  bf16_t* Qp   = xb;
  bf16_t* attn = qkv;

  // 1. convert x
  k_cvt_bf16<<<dim3((Mc * Cdim) / 2048), dim3(256), 0, stream>>>(x, xb);
  // 2. transpose-convert weights: fused QKV (1 launch) + Wo
  k_wqkv_trans<<<dim3(Cdim / 64, Nqkv / 64), dim3(256), 0, stream>>>(Wq, Wk, Wv, Wqkvt);
  k_w_trans<<<dim3((Hc * HDc) / 64, Cdim / 64), dim3(256), 0, stream>>>(Wo, Wot, Hc * HDc, Cdim);
  // 3. fused QKV projection: [4096 x 3072]
  k_gemm_bt<bf16_t><<<dim3(Nqkv / 128, Mc / 128), dim3(256), 0, stream>>>(
      xb, Wqkvt, qkv, Mc, Nqkv, Cdim);
  // 4. fused RoPE Q+K (Q overwrites xb — safe, proj done)
  k_rope2<<<dim3((Bc * Tc * 20 * 64) / 256), dim3(256), 0, stream>>>(
      qkv, cosT, sinT, Qp, Kp);
  // 5. V transpose
  k_vtrans<<<dim3(Tc / 64, KVc, Bc), dim3(256), 0, stream>>>(qkv, Vt, Nqkv, 2560);
  // 6. attention (512 blocks x 512 threads; CU-paired qt for balance)
  k_attn<<<dim3(16, Hc, Bc), dim3(512), 0, stream>>>(Qp, Kp, Vt, attn);
  // 7. output projection, fp32 out
  k_gemm_bt<float><<<dim3(Cdim / 128, Mc / 128), dim3(256), 0, stream>>>(
      attn, Wot, out, Mc, Cdim, Hc * HDc);
}